// Round 1
// baseline (346.839 us; speedup 1.0000x reference)
//
#include <hip/hip_runtime.h>
#include <hip/hip_bf16.h>

#define N_GRAPHS 100000
#define NT 8
#define MAXD 128
#define FEAT 256

typedef __attribute__((ext_vector_type(8))) short short8;
typedef __attribute__((ext_vector_type(4))) float f32x4;

__device__ __forceinline__ unsigned short f2bf(float f) {
    unsigned u = __builtin_bit_cast(unsigned, f);
    u = (u + 0x7fffu + ((u >> 16) & 1u)) >> 16;   // round-to-nearest-even
    return (unsigned short)u;
}

// One block: 4 waves, 64 graph-rows of one type, all 256 output features.
// Wave w owns output cols [w*64, w*64+64); B slice held in registers.
// A tile (64 x K32) staged f32->bf16 in LDS (row stride 136 shorts, padded).
template<int KS>
__global__ __launch_bounds__(256)
void node_enc_kernel(const float* __restrict__ x,
                     const float* __restrict__ W,
                     const float* __restrict__ bias_g,
                     float* __restrict__ out,
                     int tmap, int dmap)
{
    constexpr int K32 = KS * 32;
    const int t   = (tmap >> (8 * blockIdx.y)) & 0xff;
    const int dim = (dmap >> (8 * blockIdx.y)) & 0xff;
    const int tid  = threadIdx.x;
    const int lane = tid & 63;
    const int wave = tid >> 6;
    const int n0   = wave * 64;
    const int cgrp = lane >> 4;   // 0..3 : k-half selector / row-group
    const int c16  = lane & 15;   // A-row / B-col / C-col within 16x16 tile

    __shared__ unsigned short As[64][136];

    // --- B fragments: W[t][col][k..k+7], masked beyond dim, bf16 in regs ---
    short8 Bf[KS][4];
    float bias[4];
    const float* Wt = W + (size_t)t * FEAT * MAXD;
    #pragma unroll
    for (int nt = 0; nt < 4; ++nt) {
        const int col = n0 + nt * 16 + c16;
        bias[nt] = bias_g[t * FEAT + col];
        #pragma unroll
        for (int ks = 0; ks < KS; ++ks) {
            const int k = ks * 32 + cgrp * 8;
            const float* wp = Wt + (size_t)col * MAXD + k;
            f32x4 w0 = *(const f32x4*)wp;
            f32x4 w1 = *(const f32x4*)(wp + 4);
            short8 s;
            #pragma unroll
            for (int j = 0; j < 4; ++j) {
                s[j]     = (k + j     < dim) ? (short)f2bf(w0[j]) : (short)0;
                s[j + 4] = (k + j + 4 < dim) ? (short)f2bf(w1[j]) : (short)0;
            }
            Bf[ks][nt] = s;
        }
    }

    const int grow0 = blockIdx.x * 64;

    // --- stage A tile: 64 rows x K32 cols, f32 -> bf16 -> LDS ---
    {
        constexpr int TPR = K32 / 8;     // threads per row (8 floats each)
        constexpr int RPP = 256 / TPR;   // rows per pass
        constexpr int PASSES = 64 / RPP;
        const int rloc = tid / TPR;
        const int kg   = tid % TPR;
        #pragma unroll
        for (int p = 0; p < PASSES; ++p) {
            const int i = p * RPP + rloc;
            const int g = grow0 + i;
            f32x4 v0 = {0.f,0.f,0.f,0.f}, v1 = {0.f,0.f,0.f,0.f};
            if (g < N_GRAPHS) {
                const float* rp = x + ((size_t)g * NT + t) * MAXD + kg * 8;
                v0 = *(const f32x4*)rp;
                v1 = *(const f32x4*)(rp + 4);
            }
            short8 s;
            #pragma unroll
            for (int j = 0; j < 4; ++j) {
                s[j]     = (short)f2bf(v0[j]);
                s[j + 4] = (short)f2bf(v1[j]);
            }
            *(short8*)&As[i][kg * 8] = s;
        }
    }
    __syncthreads();

    // --- compute: 4 M-subtiles of 16 rows each ---
    #pragma unroll
    for (int ms = 0; ms < 4; ++ms) {
        short8 a[KS];
        #pragma unroll
        for (int ks = 0; ks < KS; ++ks)
            a[ks] = *(const short8*)&As[ms * 16 + c16][ks * 32 + cgrp * 8];

        f32x4 acc[4] = {{0,0,0,0},{0,0,0,0},{0,0,0,0},{0,0,0,0}};
        #pragma unroll
        for (int ks = 0; ks < KS; ++ks) {
            #pragma unroll
            for (int nt = 0; nt < 4; ++nt)
                acc[nt] = __builtin_amdgcn_mfma_f32_16x16x32_bf16(a[ks], Bf[ks][nt], acc[nt], 0, 0, 0);
        }

        #pragma unroll
        for (int nt = 0; nt < 4; ++nt) {
            const int col = n0 + nt * 16 + c16;
            #pragma unroll
            for (int r = 0; r < 4; ++r) {
                const int g = grow0 + ms * 16 + cgrp * 4 + r;
                if (g < N_GRAPHS)
                    out[((size_t)g * NT + t) * FEAT + col] = acc[nt][r] + bias[nt];
            }
        }
    }
}

extern "C" void kernel_launch(void* const* d_in, const int* in_sizes, int n_in,
                              void* d_out, int out_size, void* d_ws, size_t ws_size,
                              hipStream_t stream)
{
    const float* x = (const float*)d_in[0];
    const float* W = (const float*)d_in[1];
    const float* b = (const float*)d_in[2];
    float* out = (float*)d_out;

    const int chunks = (N_GRAPHS + 63) / 64;  // 1563

    // dims = {16,32,64,128,64,32,16,128}
    // KS=1 (dim<=32): types {0,1,5,6}; KS=2 (dim 64): {2,4}; KS=4 (dim 128): {3,7}
    node_enc_kernel<1><<<dim3(chunks, 4), 256, 0, stream>>>(x, W, b, out,
        0 | (1 << 8) | (5 << 16) | (6 << 24),
        16 | (32 << 8) | (32 << 16) | (16 << 24));
    node_enc_kernel<2><<<dim3(chunks, 2), 256, 0, stream>>>(x, W, b, out,
        2 | (4 << 8), 64 | (64 << 8));
    node_enc_kernel<4><<<dim3(chunks, 2), 256, 0, stream>>>(x, W, b, out,
        3 | (7 << 8), 128 | (128 << 8));
}

// Round 2
// 339.844 us; speedup vs baseline: 1.0206x; 1.0206x over previous
//
#include <hip/hip_runtime.h>
#include <hip/hip_bf16.h>

#define N_GRAPHS 100000
#define NT 8
#define MAXD 128
#define FEAT 256

typedef __attribute__((ext_vector_type(8))) short short8;
typedef __attribute__((ext_vector_type(4))) float f32x4;

__device__ __forceinline__ unsigned short f2bf(float f) {
    unsigned u = __builtin_bit_cast(unsigned, f);
    u = (u + 0x7fffu + ((u >> 16) & 1u)) >> 16;   // round-to-nearest-even
    return (unsigned short)u;
}

// One block: 4 waves, 128 graph-rows of one type, all 256 output features.
// Wave w owns output cols [w*64, w*64+64); B slice held in registers (bf16),
// loaded from W (f32, L2-resident — x/out use non-temporal to avoid evicting it).
// A tile (128 x K32) staged f32->bf16 in LDS (row stride K32+8 shorts, padded).
template<int KS>
__global__ __launch_bounds__(256, 4)
void node_enc_kernel(const float* __restrict__ x,
                     const float* __restrict__ W,
                     const float* __restrict__ bias_g,
                     float* __restrict__ out,
                     int tmap, int dmap)
{
    constexpr int K32  = KS * 32;
    constexpr int ROWS = 128;
    const int t   = (tmap >> (8 * blockIdx.y)) & 0xff;
    const int dim = (dmap >> (8 * blockIdx.y)) & 0xff;
    const int tid  = threadIdx.x;
    const int lane = tid & 63;
    const int wave = tid >> 6;
    const int n0   = wave * 64;
    const int cgrp = lane >> 4;   // 0..3 : k-chunk selector / C row-group
    const int c16  = lane & 15;   // A-row / B-col / C-col within 16x16 tile

    __shared__ unsigned short As[ROWS][K32 + 8];

    // --- B fragments: W[t][col][k..k+7], masked beyond dim, bf16 in regs ---
    short8 Bf[KS][4];
    float bias[4];
    const float* Wt = W + (size_t)t * FEAT * MAXD;
    #pragma unroll
    for (int nt = 0; nt < 4; ++nt) {
        const int col = n0 + nt * 16 + c16;
        bias[nt] = bias_g[t * FEAT + col];
        #pragma unroll
        for (int ks = 0; ks < KS; ++ks) {
            const int k = ks * 32 + cgrp * 8;
            const float* wp = Wt + (size_t)col * MAXD + k;
            f32x4 w0 = *(const f32x4*)wp;
            f32x4 w1 = *(const f32x4*)(wp + 4);
            short8 s;
            #pragma unroll
            for (int j = 0; j < 4; ++j) {
                s[j]     = (k + j     < dim) ? (short)f2bf(w0[j]) : (short)0;
                s[j + 4] = (k + j + 4 < dim) ? (short)f2bf(w1[j]) : (short)0;
            }
            Bf[ks][nt] = s;
        }
    }

    const int grow0 = blockIdx.x * ROWS;

    // --- stage A tile: ROWS x K32, f32 -> bf16 -> LDS (non-temporal loads) ---
    {
        constexpr int TPR    = K32 / 8;     // threads per row (8 floats each)
        constexpr int RPP    = 256 / TPR;   // rows per pass
        constexpr int PASSES = ROWS / RPP;
        const int rloc = tid / TPR;
        const int kg   = tid % TPR;
        const bool kload = (kg * 8 < dim);  // skip cols beyond true dim (dim16 in KS=1)
        #pragma unroll
        for (int p = 0; p < PASSES; ++p) {
            const int i = p * RPP + rloc;
            const int g = grow0 + i;
            f32x4 v0 = {0.f,0.f,0.f,0.f}, v1 = {0.f,0.f,0.f,0.f};
            if (kload && g < N_GRAPHS) {
                const float* rp = x + ((size_t)g * NT + t) * MAXD + kg * 8;
                v0 = __builtin_nontemporal_load((const f32x4*)rp);
                v1 = __builtin_nontemporal_load((const f32x4*)rp + 1);
            }
            short8 s;
            #pragma unroll
            for (int j = 0; j < 4; ++j) {
                s[j]     = (short)f2bf(v0[j]);
                s[j + 4] = (short)f2bf(v1[j]);
            }
            *(short8*)&As[i][kg * 8] = s;
        }
    }
    __syncthreads();

    const bool full = (grow0 + ROWS <= N_GRAPHS);

    // --- compute: ROWS/16 M-subtiles of 16 rows each ---
    #pragma unroll
    for (int ms = 0; ms < ROWS / 16; ++ms) {
        short8 a[KS];
        #pragma unroll
        for (int ks = 0; ks < KS; ++ks)
            a[ks] = *(const short8*)&As[ms * 16 + c16][ks * 32 + cgrp * 8];

        f32x4 acc[4] = {{0,0,0,0},{0,0,0,0},{0,0,0,0},{0,0,0,0}};
        #pragma unroll
        for (int ks = 0; ks < KS; ++ks) {
            #pragma unroll
            for (int nt = 0; nt < 4; ++nt)
                acc[nt] = __builtin_amdgcn_mfma_f32_16x16x32_bf16(a[ks], Bf[ks][nt], acc[nt], 0, 0, 0);
        }

        if (full) {
            #pragma unroll
            for (int nt = 0; nt < 4; ++nt) {
                const int col = n0 + nt * 16 + c16;
                #pragma unroll
                for (int r = 0; r < 4; ++r) {
                    const int g = grow0 + ms * 16 + cgrp * 4 + r;
                    __builtin_nontemporal_store(acc[nt][r] + bias[nt],
                        &out[((size_t)g * NT + t) * FEAT + col]);
                }
            }
        } else {
            #pragma unroll
            for (int nt = 0; nt < 4; ++nt) {
                const int col = n0 + nt * 16 + c16;
                #pragma unroll
                for (int r = 0; r < 4; ++r) {
                    const int g = grow0 + ms * 16 + cgrp * 4 + r;
                    if (g < N_GRAPHS)
                        __builtin_nontemporal_store(acc[nt][r] + bias[nt],
                            &out[((size_t)g * NT + t) * FEAT + col]);
                }
            }
        }
    }
}

extern "C" void kernel_launch(void* const* d_in, const int* in_sizes, int n_in,
                              void* d_out, int out_size, void* d_ws, size_t ws_size,
                              hipStream_t stream)
{
    const float* x = (const float*)d_in[0];
    const float* W = (const float*)d_in[1];
    const float* b = (const float*)d_in[2];
    float* out = (float*)d_out;

    const int chunks = (N_GRAPHS + 127) / 128;  // 782

    // dims = {16,32,64,128,64,32,16,128}
    // KS=1 (dim<=32): types {0,1,5,6}; KS=2 (dim 64): {2,4}; KS=4 (dim 128): {3,7}
    node_enc_kernel<1><<<dim3(chunks, 4), 256, 0, stream>>>(x, W, b, out,
        0 | (1 << 8) | (5 << 16) | (6 << 24),
        16 | (32 << 8) | (32 << 16) | (16 << 24));
    node_enc_kernel<2><<<dim3(chunks, 2), 256, 0, stream>>>(x, W, b, out,
        2 | (4 << 8), 64 | (64 << 8));
    node_enc_kernel<4><<<dim3(chunks, 2), 256, 0, stream>>>(x, W, b, out,
        3 | (7 << 8), 128 | (128 << 8));
}

// Round 4
// 304.981 us; speedup vs baseline: 1.1372x; 1.1143x over previous
//
#include <hip/hip_runtime.h>
#include <hip/hip_bf16.h>

#define N_GRAPHS 100000
#define NTYPES 8
#define MAXD 128
#define FEAT 256
#define ROWS 64

typedef __attribute__((ext_vector_type(8))) short short8;
typedef __attribute__((ext_vector_type(4))) float f32x4;
typedef __attribute__((ext_vector_type(4))) unsigned uint4v;

constexpr int DIMS[NTYPES] = {16, 32, 64, 128, 64, 32, 16, 128};

__device__ __forceinline__ unsigned f2bf_u(float f) {
    unsigned u = __builtin_bit_cast(unsigned, f);
    return (u + 0x7fffu + ((u >> 16) & 1u)) >> 16;   // round-to-nearest-even
}
__device__ __forceinline__ unsigned cvt2(float lo, float hi) {
    return f2bf_u(lo) | (f2bf_u(hi) << 16);
}
__device__ __forceinline__ short8 cvt8(f32x4 a, f32x4 b) {
    uint4v u;
    u.x = cvt2(a.x, a.y); u.y = cvt2(a.z, a.w);
    u.z = cvt2(b.x, b.y); u.w = cvt2(b.z, b.w);
    return __builtin_bit_cast(short8, u);
}

// --- W -> bf16 MFMA-fragment prepack (runs every launch; deterministic) ---
// Layout: wp[((((t*4 + wave)*4 + nt)*4 + ks)*4 + cgrp)*16 + c16] = short8 of
// W[t][wave*64 + nt*16 + c16][ks*32 + cgrp*8 .. +7], zero-masked at k >= dim.
__global__ __launch_bounds__(256)
void prepack_w(const float* __restrict__ W, short8* __restrict__ wp)
{
    const int idx  = blockIdx.x * 256 + threadIdx.x;   // 32768 total
    const int c16  = idx & 15;
    const int cgrp = (idx >> 4) & 3;
    const int ks   = (idx >> 6) & 3;
    const int nt   = (idx >> 8) & 3;
    const int wb   = (idx >> 10) & 3;
    const int t    = (idx >> 12) & 7;
    const int col  = wb * 64 + nt * 16 + c16;
    const int k    = ks * 32 + cgrp * 8;
    const int dim  = 16 << ((0x30123210u >> (4 * t)) & 0xf);  // {16,32,64,128,64,32,16,128}
    const float* src = W + ((size_t)t * FEAT + col) * MAXD + k;
    f32x4 a = *(const f32x4*)src;
    f32x4 b = *(const f32x4*)(src + 4);
    #pragma unroll
    for (int j = 0; j < 4; ++j) {
        if (k + j     >= dim) a[j] = 0.f;
        if (k + 4 + j >= dim) b[j] = 0.f;
    }
    wp[idx] = cvt8(a, b);
}

// --- stage one type's A tile: ROWS x K32, f32 -> bf16 -> LDS ---
template<int K32>
__device__ __forceinline__ void stage_tile(const float* __restrict__ x, int grow0, int t,
                                           unsigned short (* __restrict__ As)[136], int tid)
{
    constexpr int TPR    = K32 / 8;     // threads per row
    constexpr int RPP    = 256 / TPR;   // rows per pass
    constexpr int PASSES = ROWS / RPP;
    const int rloc = tid / TPR;
    const int kg   = tid % TPR;
    #pragma unroll
    for (int p = 0; p < PASSES; ++p) {
        const int i = p * RPP + rloc;
        int g = grow0 + i;
        if (g >= N_GRAPHS) g = N_GRAPHS - 1;   // clamp; tail stores are guarded
        const float* rp = x + ((size_t)g * NTYPES + t) * MAXD + kg * 8;
        f32x4 v0 = __builtin_nontemporal_load((const f32x4*)rp);
        f32x4 v1 = __builtin_nontemporal_load((const f32x4*)rp + 1);
        *(short8*)&As[i][kg * 8] = cvt8(v0, v1);
    }
}

template<int T, bool PRE>
__device__ __forceinline__ void type_step(const float* __restrict__ x,
                                          const float* __restrict__ W,
                                          const float* __restrict__ bias_g,
                                          float* __restrict__ out,
                                          const short8* __restrict__ wp,
                                          unsigned short (* __restrict__ As)[ROWS][136],
                                          int grow0, int tid, bool full)
{
    constexpr int DIM = DIMS[T];
    constexpr int KS  = (DIM + 31) / 32;
    const int lane = tid & 63, wave = tid >> 6;
    const int cgrp = lane >> 4, c16 = lane & 15;
    const int n0   = wave * 64;

    short8 Bf[KS][4];
    float  bias[4];
    #pragma unroll
    for (int nt = 0; nt < 4; ++nt) {
        bias[nt] = bias_g[T * FEAT + n0 + nt * 16 + c16];
        if constexpr (PRE) {
            #pragma unroll
            for (int ks = 0; ks < KS; ++ks)
                Bf[ks][nt] = wp[((((T * 4 + wave) * 4 + nt) * 4 + ks) * 4 + cgrp) * 16 + c16];
        } else {
            const int col = n0 + nt * 16 + c16;
            #pragma unroll
            for (int ks = 0; ks < KS; ++ks) {
                const int k = ks * 32 + cgrp * 8;
                const float* wpf = W + ((size_t)T * FEAT + col) * MAXD + k;
                f32x4 w0 = *(const f32x4*)wpf;
                f32x4 w1 = *(const f32x4*)(wpf + 4);
                #pragma unroll
                for (int j = 0; j < 4; ++j) {
                    if (k + j     >= DIM) w0[j] = 0.f;
                    if (k + 4 + j >= DIM) w1[j] = 0.f;
                }
                Bf[ks][nt] = cvt8(w0, w1);
            }
        }
    }

    __syncthreads();   // staging(T) complete; also orders WAR on buffer (T+1)&1

    if constexpr (T + 1 < NTYPES)
        stage_tile<((DIMS[T + 1] + 31) / 32) * 32>(x, grow0, T + 1, As[(T + 1) & 1], tid);

    const unsigned short (* __restrict__ A)[136] = As[T & 1];
    #pragma unroll
    for (int ms = 0; ms < ROWS / 16; ++ms) {
        short8 a[KS];
        #pragma unroll
        for (int ks = 0; ks < KS; ++ks)
            a[ks] = *(const short8*)&A[ms * 16 + c16][ks * 32 + cgrp * 8];

        f32x4 acc[4] = {{0,0,0,0},{0,0,0,0},{0,0,0,0},{0,0,0,0}};
        #pragma unroll
        for (int ks = 0; ks < KS; ++ks) {
            #pragma unroll
            for (int nt = 0; nt < 4; ++nt)
                acc[nt] = __builtin_amdgcn_mfma_f32_16x16x32_bf16(a[ks], Bf[ks][nt], acc[nt], 0, 0, 0);
        }

        if (full) {
            #pragma unroll
            for (int nt = 0; nt < 4; ++nt) {
                const int col = n0 + nt * 16 + c16;
                #pragma unroll
                for (int r = 0; r < 4; ++r) {
                    const int g = grow0 + ms * 16 + cgrp * 4 + r;
                    __builtin_nontemporal_store(acc[nt][r] + bias[nt],
                        &out[((size_t)g * NTYPES + T) * FEAT + col]);
                }
            }
        } else {
            #pragma unroll
            for (int nt = 0; nt < 4; ++nt) {
                const int col = n0 + nt * 16 + c16;
                #pragma unroll
                for (int r = 0; r < 4; ++r) {
                    const int g = grow0 + ms * 16 + cgrp * 4 + r;
                    if (g < N_GRAPHS)
                        __builtin_nontemporal_store(acc[nt][r] + bias[nt],
                            &out[((size_t)g * NTYPES + T) * FEAT + col]);
                }
            }
        }
    }

    if constexpr (T + 1 < NTYPES)
        type_step<T + 1, PRE>(x, W, bias_g, out, wp, As, grow0, tid, full);
}

// One block: 4 waves, 64 graphs, ALL 8 types -> writes a dense contiguous
// 512 KB output region. A tiles double-buffered in LDS, one barrier per type.
template<bool PRE>
__global__ __launch_bounds__(256, 4)
void node_enc_fused(const float* __restrict__ x, const float* __restrict__ W,
                    const float* __restrict__ bias_g, float* __restrict__ out,
                    const short8* __restrict__ wp)
{
    __shared__ __align__(16) unsigned short As[2][ROWS][136];
    const int tid   = threadIdx.x;
    const int grow0 = blockIdx.x * ROWS;
    const bool full = (grow0 + ROWS <= N_GRAPHS);

    stage_tile<((DIMS[0] + 31) / 32) * 32>(x, grow0, 0, As[0], tid);
    type_step<0, PRE>(x, W, bias_g, out, wp, As, grow0, tid, full);
}

extern "C" void kernel_launch(void* const* d_in, const int* in_sizes, int n_in,
                              void* d_out, int out_size, void* d_ws, size_t ws_size,
                              hipStream_t stream)
{
    const float* x = (const float*)d_in[0];
    const float* W = (const float*)d_in[1];
    const float* b = (const float*)d_in[2];
    float* out = (float*)d_out;

    const int chunks = (N_GRAPHS + ROWS - 1) / ROWS;   // 1563
    const size_t wp_bytes = (size_t)NTYPES * 4 * 4 * 4 * 4 * 16 * sizeof(short8);  // 512 KB

    if (ws_size >= wp_bytes) {
        short8* wp = (short8*)d_ws;
        prepack_w<<<128, 256, 0, stream>>>(W, wp);
        node_enc_fused<true><<<chunks, 256, 0, stream>>>(x, W, b, out, wp);
    } else {
        node_enc_fused<false><<<chunks, 256, 0, stream>>>(x, W, b, out, nullptr);
    }
}